// Round 7
// baseline (638.079 us; speedup 1.0000x reference)
//
#include <hip/hip_runtime.h>

#define D 128
#define NG 256

typedef __attribute__((ext_vector_type(8))) short bf16x8;
typedef __attribute__((ext_vector_type(4))) float f32x4;
typedef __attribute__((ext_vector_type(4))) float f4;
typedef __attribute__((ext_vector_type(2))) int i2;
typedef __attribute__((ext_vector_type(4))) ushort u16x4;

__device__ inline ushort f2bf(float f) {
  uint b = __float_as_uint(f);
  return (ushort)((b + 0x7fffu + ((b >> 16) & 1u)) >> 16);
}
__device__ inline float bf2f(ushort u) { return __uint_as_float((uint)u << 16); }

// ------- fused: deg histogram + per-graph counts + x->bf16 + W->bf16^T -------
__global__ __launch_bounds__(256) void prep_kernel(
    const int* __restrict__ ei, int* __restrict__ deg,
    const int* __restrict__ batch, const int* __restrict__ primary,
    int* __restrict__ ncount, int* __restrict__ ccnt,
    const float* __restrict__ x, ushort* __restrict__ xb,
    const float* __restrict__ W1, const float* __restrict__ W2,
    ushort* __restrict__ W1T, ushort* __restrict__ W2T, int E, int N, int total4) {
  int i = blockIdx.x * blockDim.x + threadIdx.x;
  if (i < E) atomicAdd(&deg[ei[E + i]], 1);
  if (i < N) {
    int g = batch[i];
    atomicAdd(&ncount[g], 1);
    if (primary[i] == 0) atomicAdd(&ccnt[g], 1);
  }
  if (i < total4) {
    f4 v = __builtin_nontemporal_load(&((const f4*)x)[i]);
    u16x4 o;
    o.x = f2bf(v.x); o.y = f2bf(v.y); o.z = f2bf(v.z); o.w = f2bf(v.w);
    ((u16x4*)xb)[i] = o;
  }
  if (i < 2 * D * D) {
    int w = i >> 14;
    int k = (i >> 7) & 127;
    int n = i & 127;
    const float* src = w ? W2 : W1;
    ushort* dst = w ? W2T : W1T;
    dst[n * 128 + k] = f2bf(src[k * 128 + n]);
  }
}

// ---------------- scan over N (3-phase) ----------------
__global__ __launch_bounds__(256) void scan_block_sums(const int* __restrict__ deg,
                                                       int* __restrict__ bsum, int N) {
  __shared__ int red[256];
  int t = threadIdx.x;
  int base = blockIdx.x * 1024;
  int s = 0;
#pragma unroll
  for (int j = 0; j < 4; ++j) {
    int i = base + t * 4 + j;
    if (i < N) s += deg[i];
  }
  red[t] = s;
  __syncthreads();
  for (int o = 128; o > 0; o >>= 1) {
    if (t < o) red[t] += red[t + o];
    __syncthreads();
  }
  if (t == 0) bsum[blockIdx.x] = red[0];
}

// parallel exclusive scan of nb (<=128) block sums
__global__ void scan_bsum(int* __restrict__ bsum, int nb) {
  __shared__ int a[128];
  int t = threadIdx.x;
  int v = (t < nb) ? bsum[t] : 0;
  a[t] = v;
  __syncthreads();
  for (int o = 1; o < 128; o <<= 1) {
    int u = (t >= o) ? a[t - o] : 0;
    __syncthreads();
    a[t] += u;
    __syncthreads();
  }
  if (t < nb) bsum[t] = a[t] - v;
}

__global__ __launch_bounds__(256) void scan_final(const int* __restrict__ deg,
                                                  const int* __restrict__ bsum,
                                                  int* __restrict__ off, int N) {
  __shared__ int ts[256];
  int t = threadIdx.x;
  int base = blockIdx.x * 1024;
  int v[4];
  int s = 0;
#pragma unroll
  for (int j = 0; j < 4; ++j) {
    int i = base + t * 4 + j;
    v[j] = (i < N) ? deg[i] : 0;
    s += v[j];
  }
  ts[t] = s;
  __syncthreads();
  for (int o = 1; o < 256; o <<= 1) {
    int u = (t >= o) ? ts[t - o] : 0;
    __syncthreads();
    ts[t] += u;
    __syncthreads();
  }
  int excl = ts[t] - s + bsum[blockIdx.x];
#pragma unroll
  for (int j = 0; j < 4; ++j) {
    int i = base + t * 4 + j;
    if (i < N) off[i] = excl;
    excl += v[j];
    if (i == N - 1) off[N] = excl;
  }
}

// ---------------- CSR fill: csr[off[dst]+slot] = (src, e) ----------------
__global__ __launch_bounds__(256) void fill_kernel(const int* __restrict__ ei,
                                                   const int* __restrict__ off,
                                                   int* __restrict__ cursor,
                                                   i2* __restrict__ csr, int E) {
  int e = blockIdx.x * blockDim.x + threadIdx.x;
  if (e >= E) return;
  int s = ei[e];
  int d = ei[E + e];
  int slot = atomicAdd(&cursor[d], 1);
  i2 v;
  v.x = s;
  v.y = e;
  csr[off[d] + slot] = v;
}

// ---------------- Gather: full wave per row, 2 edges/instr, 8 in flight -------------
// yb[n] = bf16( x_bf[n] + sum_{e:(s->n)} (x_bf[s] + ea[e]) )
__global__ __launch_bounds__(256, 8) void gather_kernel(const ushort* __restrict__ xb,
                                                        const float* __restrict__ ea,
                                                        const i2* __restrict__ csr,
                                                        const int* __restrict__ off,
                                                        ushort* __restrict__ yb, int N) {
  const int lane = threadIdx.x & 63;
  const int h = lane >> 5;  // which edge of a pair
  const int c = lane & 31;  // column chunk (f4 / u16x4)
  const int wave = (blockIdx.x * 256 + (threadIdx.x & ~63)) >> 6;
  const f4* ea4 = (const f4*)ea;
  const u16x4* xb4 = (const u16x4*)xb;
  const int row0 = wave * 4;
#pragma unroll 1
  for (int r = 0; r < 4; ++r) {
    const int n = row0 + r;
    if (n >= N) return;
    f4 acc = {0.f, 0.f, 0.f, 0.f};
    int k = off[n];
    const int e = off[n + 1];
#pragma unroll 1
    for (; k + 8 <= e; k += 8) {
      i2 p0 = csr[k + h];
      i2 p1 = csr[k + 2 + h];
      i2 p2 = csr[k + 4 + h];
      i2 p3 = csr[k + 6 + h];
      f4 a0 = __builtin_nontemporal_load(&ea4[(size_t)p0.y * 32 + c]);
      f4 a1 = __builtin_nontemporal_load(&ea4[(size_t)p1.y * 32 + c]);
      f4 a2 = __builtin_nontemporal_load(&ea4[(size_t)p2.y * 32 + c]);
      f4 a3 = __builtin_nontemporal_load(&ea4[(size_t)p3.y * 32 + c]);
      u16x4 u0 = xb4[(size_t)p0.x * 32 + c];
      u16x4 u1 = xb4[(size_t)p1.x * 32 + c];
      u16x4 u2 = xb4[(size_t)p2.x * 32 + c];
      u16x4 u3 = xb4[(size_t)p3.x * 32 + c];
      acc.x += (a0.x + bf2f(u0.x)) + (a1.x + bf2f(u1.x));
      acc.y += (a0.y + bf2f(u0.y)) + (a1.y + bf2f(u1.y));
      acc.z += (a0.z + bf2f(u0.z)) + (a1.z + bf2f(u1.z));
      acc.w += (a0.w + bf2f(u0.w)) + (a1.w + bf2f(u1.w));
      acc.x += (a2.x + bf2f(u2.x)) + (a3.x + bf2f(u3.x));
      acc.y += (a2.y + bf2f(u2.y)) + (a3.y + bf2f(u3.y));
      acc.z += (a2.z + bf2f(u2.z)) + (a3.z + bf2f(u3.z));
      acc.w += (a2.w + bf2f(u2.w)) + (a3.w + bf2f(u3.w));
    }
#pragma unroll 1
    for (; k + 2 <= e; k += 2) {
      i2 p0 = csr[k + h];
      f4 a0 = __builtin_nontemporal_load(&ea4[(size_t)p0.y * 32 + c]);
      u16x4 u0 = xb4[(size_t)p0.x * 32 + c];
      acc.x += a0.x + bf2f(u0.x);
      acc.y += a0.y + bf2f(u0.y);
      acc.z += a0.z + bf2f(u0.z);
      acc.w += a0.w + bf2f(u0.w);
    }
    if (k + h < e) {  // odd tail (h==0 only reachable)
      i2 p0 = csr[k + h];
      f4 a0 = __builtin_nontemporal_load(&ea4[(size_t)p0.y * 32 + c]);
      u16x4 u0 = xb4[(size_t)p0.x * 32 + c];
      acc.x += a0.x + bf2f(u0.x);
      acc.y += a0.y + bf2f(u0.y);
      acc.z += a0.z + bf2f(u0.z);
      acc.w += a0.w + bf2f(u0.w);
    }
    // cross-half reduce: lane c gets lane c+32's partial
    acc.x += __shfl_xor(acc.x, 32, 64);
    acc.y += __shfl_xor(acc.y, 32, 64);
    acc.z += __shfl_xor(acc.z, 32, 64);
    acc.w += __shfl_xor(acc.w, 32, 64);
    if (h == 0) {
      u16x4 self = xb4[(size_t)n * 32 + c];
      acc.x += bf2f(self.x);
      acc.y += bf2f(self.y);
      acc.z += bf2f(self.z);
      acc.w += bf2f(self.w);
      u16x4 o;
      o.x = f2bf(acc.x); o.y = f2bf(acc.y); o.z = f2bf(acc.z); o.w = f2bf(acc.w);
      __builtin_nontemporal_store(o, &((u16x4*)yb)[(size_t)n * 32 + c]);
    }
  }
}

// ---------------- exclusive scan of graph sizes -> gstart ----------------
__global__ void scan_kernel(const int* __restrict__ ncount, int* __restrict__ gstart) {
  __shared__ int a[NG];
  int tx = threadIdx.x;
  int v = ncount[tx];
  a[tx] = v;
  __syncthreads();
  for (int off = 1; off < NG; off <<= 1) {
    int u = (tx >= off) ? a[tx - off] : 0;
    __syncthreads();
    a[tx] += u;
    __syncthreads();
  }
  gstart[tx] = a[tx] - v;
  if (tx == NG - 1) gstart[NG] = a[tx];
}

// ---------------- per-graph stable ranks: primary -> p, cond -> ~p ----------------
__global__ __launch_bounds__(256) void rank_kernel(const int* __restrict__ primary,
                                                   const int* __restrict__ gstart,
                                                   const int* __restrict__ ccnt,
                                                   int* __restrict__ pos) {
  int g = blockIdx.x;
  int s = gstart[g], e = gstart[g + 1];
  int pcnt = (e - s) - ccnt[g];
  __shared__ int wcntP[4], wcntC[4];
  int prun = 0, crun = 0;
  for (int i0 = s; i0 < e; i0 += 256) {
    int n = i0 + threadIdx.x;
    bool valid = n < e;
    int isP = (valid && primary[n] == 1) ? 1 : 0;
    int isC = (valid && primary[n] != 1) ? 1 : 0;
    unsigned long long mP = __ballot(isP);
    unsigned long long mC = __ballot(isC);
    int lane = threadIdx.x & 63;
    int wid = threadIdx.x >> 6;
    if (lane == 0) { wcntP[wid] = __popcll(mP); wcntC[wid] = __popcll(mC); }
    __syncthreads();
    int preP = __popcll(mP & ((1ULL << lane) - 1ULL));
    int preC = __popcll(mC & ((1ULL << lane) - 1ULL));
    int woffP = 0, woffC = 0;
#pragma unroll
    for (int ww = 0; ww < 4; ++ww)
      if (ww < wid) { woffP += wcntP[ww]; woffC += wcntC[ww]; }
    int totP = wcntP[0] + wcntP[1] + wcntP[2] + wcntP[3];
    int totC = wcntC[0] + wcntC[1] + wcntC[2] + wcntC[3];
    if (valid) {
      if (isP)
        pos[n] = s + prun + woffP + preP;
      else
        pos[n] = ~(s + pcnt + crun + woffC + preC);
    }
    prun += totP;
    crun += totC;
    __syncthreads();
  }
}

// ---------------- MFMA MLP: writes out rows directly + fused cond-pool sum ----------------
__global__ __launch_bounds__(256) void mlp_mfma_kernel(
    const ushort* __restrict__ yb, float* __restrict__ out,
    const ushort* __restrict__ W1T, const float* __restrict__ b1,
    const ushort* __restrict__ W2T, const float* __restrict__ b2,
    const int* __restrict__ batch, const int* __restrict__ primary,
    const int* __restrict__ pos, float* __restrict__ csum, int N) {
  __shared__ ushort tl[4][16][D];  // per-wave relu(t) tile, XOR-swizzled cols
  __shared__ float csl[4][D];      // local csum for up to 4 graphs
  const int tid = threadIdx.x;
  const int w = tid >> 6;
  const int l = tid & 63;
  const int lr = l & 15;
  const int lg = l >> 4;
  const int base = blockIdx.x * 64;
  const int m0 = base + w * 16;

  for (int i = tid; i < 4 * D; i += 256) ((float*)csl)[i] = 0.f;
  int gmin = batch[base < N ? base : N - 1];
  __syncthreads();

  // GEMM1: t = relu(y @ W1 + b1)
  f32x4 acc[8];
#pragma unroll
  for (int t = 0; t < 8; ++t) {
    float bv = b1[t * 16 + lr];
    acc[t][0] = bv; acc[t][1] = bv; acc[t][2] = bv; acc[t][3] = bv;
  }
  int arow = m0 + lr;
  if (arow >= N) arow = N - 1;
#pragma unroll
  for (int kk = 0; kk < 4; ++kk) {
    bf16x8 a = *(const bf16x8*)&yb[(size_t)arow * D + kk * 32 + lg * 8];
#pragma unroll
    for (int t = 0; t < 8; ++t) {
      bf16x8 b = *(const bf16x8*)&W1T[(size_t)(t * 16 + lr) * D + kk * 32 + lg * 8];
      acc[t] = __builtin_amdgcn_mfma_f32_16x16x32_bf16(a, b, acc[t], 0, 0, 0);
    }
  }
  // relu + cvt + store to per-wave LDS tile ([m][n], col ^= (m&7)<<3)
#pragma unroll
  for (int t = 0; t < 8; ++t) {
#pragma unroll
    for (int r = 0; r < 4; ++r) {
      float v = acc[t][r];
      v = v > 0.f ? v : 0.f;
      int m = lg * 4 + r;
      int col = (t * 16 + lr) ^ ((m & 7) << 3);
      tl[w][m][col] = f2bf(v);
    }
  }
  __syncthreads();

  // GEMM2: h = t @ W2 + b2
  f32x4 acc2[8];
#pragma unroll
  for (int t = 0; t < 8; ++t) {
    float bv = b2[t * 16 + lr];
    acc2[t][0] = bv; acc2[t][1] = bv; acc2[t][2] = bv; acc2[t][3] = bv;
  }
#pragma unroll
  for (int kk = 0; kk < 4; ++kk) {
    bf16x8 a = *(const bf16x8*)&tl[w][lr][(kk * 32 + lg * 8) ^ ((lr & 7) << 3)];
#pragma unroll
    for (int t = 0; t < 8; ++t) {
      bf16x8 b = *(const bf16x8*)&W2T[(size_t)(t * 16 + lr) * D + kk * 32 + lg * 8];
      acc2[t] = __builtin_amdgcn_mfma_f32_16x16x32_bf16(a, b, acc2[t], 0, 0, 0);
    }
  }

  // epilogue: direct out-row writes + cond-pool accumulation
#pragma unroll
  for (int r = 0; r < 4; ++r) {
    int m = m0 + lg * 4 + r;
    if (m >= N) continue;
    int p = pos[m];
    if (p >= 0) {  // primary: left half = h
      size_t ro = (size_t)p * 256;
#pragma unroll
      for (int t = 0; t < 8; ++t)
        __builtin_nontemporal_store(acc2[t][r], &out[ro + t * 16 + lr]);
    } else {  // cond: zero full row, accumulate into pool sum
      size_t ro = (size_t)(~p) * 256;
#pragma unroll
      for (int t = 0; t < 8; ++t) {
        __builtin_nontemporal_store(0.0f, &out[ro + t * 16 + lr]);
        __builtin_nontemporal_store(0.0f, &out[ro + 128 + t * 16 + lr]);
      }
      int g = batch[m];
      int gl = g - gmin;
      if (gl < 4) {
#pragma unroll
        for (int t = 0; t < 8; ++t) atomicAdd(&csl[gl][t * 16 + lr], acc2[t][r]);
      } else {
#pragma unroll
        for (int t = 0; t < 8; ++t)
          unsafeAtomicAdd(&csum[(size_t)g * D + t * 16 + lr], acc2[t][r]);
      }
    }
  }
  __syncthreads();
  for (int i = tid; i < 4 * D; i += 256) {
    float v = ((float*)csl)[i];
    if (v != 0.f) {
      int gl = i >> 7, c = i & 127;
      unsafeAtomicAdd(&csum[(size_t)(gmin + gl) * D + c], v);
    }
  }
}

// ---------------- right half of primary rows: out[p][128+c] = csum[g][c]/cnt ----------------
__global__ __launch_bounds__(256) void poolwrite_kernel(const float* __restrict__ csum,
                                                        const int* __restrict__ ccnt,
                                                        const int* __restrict__ batch,
                                                        const int* __restrict__ pos,
                                                        float* __restrict__ out, int N) {
  long long tid = (long long)blockIdx.x * blockDim.x + threadIdx.x;
  int n = (int)(tid >> 5);
  int c = (int)(tid & 31);
  if (n >= N) return;
  int p = pos[n];
  if (p < 0) return;
  int g = batch[n];
  int cnt = ccnt[g];
  f4 v = {0.f, 0.f, 0.f, 0.f};
  if (cnt > 0) {
    f4 s4 = ((const f4*)csum)[(size_t)g * 32 + c];
    float inv = 1.0f / (float)cnt;
    v = s4 * inv;
  }
  __builtin_nontemporal_store(v, &((f4*)out)[(size_t)p * 64 + 32 + c]);
}

extern "C" void kernel_launch(void* const* d_in, const int* in_sizes, int n_in,
                              void* d_out, int out_size, void* d_ws, size_t ws_size,
                              hipStream_t stream) {
  const float* x = (const float*)d_in[0];
  const int* ei = (const int*)d_in[1];
  const float* ea = (const float*)d_in[2];
  const int* batch = (const int*)d_in[3];
  const int* primary = (const int*)d_in[4];
  const float* W1 = (const float*)d_in[5];
  const float* b1 = (const float*)d_in[6];
  const float* W2 = (const float*)d_in[7];
  const float* b2 = (const float*)d_in[8];
  float* out = (float*)d_out;

  const int N = in_sizes[0] / D;  // 100000
  const int E = in_sizes[1] / 2;  // 1600000
  const int nb = (N + 1023) / 1024;
  const int total4 = N * D / 4;

  // workspace layout
  float* csum = (float*)d_ws;                        // NG*D
  ushort* yb = (ushort*)(csum + (size_t)NG * D);     // N*D bf16
  ushort* xb = yb + (size_t)N * D;                   // N*D bf16
  ushort* W1T = xb + (size_t)N * D;                  // 128*128 bf16
  ushort* W2T = W1T + D * D;                         // 128*128 bf16
  i2* csr = (i2*)(W2T + D * D);                      // E int2
  int* ip = (int*)(csr + (size_t)E);
  int* deg = ip;                                     // N
  int* off = deg + N;                                // N+1 (pad 4)
  int* cursor = off + N + 4;                         // N
  int* bsum = cursor + N;                            // nb (pad 128)
  int* ccnt = bsum + 128;                            // NG
  int* ncount = ccnt + NG;                           // NG
  int* gstart = ncount + NG;                         // NG+1 (pad 260)
  int* pos = gstart + 260;                           // N

  hipMemsetAsync(csum, 0, (size_t)NG * D * 4, stream);
  hipMemsetAsync(deg, 0, (size_t)N * 4, stream);
  hipMemsetAsync(cursor, 0, (size_t)N * 4, stream);
  hipMemsetAsync(ccnt, 0, (size_t)NG * 2 * 4, stream);  // ccnt + ncount contiguous

  prep_kernel<<<(total4 + 255) / 256, 256, 0, stream>>>(ei, deg, batch, primary, ncount, ccnt,
                                                        x, xb, W1, W2, W1T, W2T, E, N, total4);
  scan_block_sums<<<nb, 256, 0, stream>>>(deg, bsum, N);
  scan_bsum<<<1, 128, 0, stream>>>(bsum, nb);
  scan_final<<<nb, 256, 0, stream>>>(deg, bsum, off, N);
  fill_kernel<<<(E + 255) / 256, 256, 0, stream>>>(ei, off, cursor, csr, E);
  scan_kernel<<<1, NG, 0, stream>>>(ncount, gstart);
  rank_kernel<<<NG, 256, 0, stream>>>(primary, gstart, ccnt, pos);
  {
    int waves = (N + 3) / 4;
    int blocks = (waves + 3) / 4;
    gather_kernel<<<blocks, 256, 0, stream>>>(xb, ea, csr, off, yb, N);
  }
  mlp_mfma_kernel<<<(N + 63) / 64, 256, 0, stream>>>(yb, out, W1T, b1, W2T, b2, batch, primary,
                                                     pos, csum, N);
  poolwrite_kernel<<<(int)(((long long)N * 32 + 255) / 256), 256, 0, stream>>>(csum, ccnt, batch,
                                                                               pos, out, N);
}